// Round 1
// baseline (710.069 us; speedup 1.0000x reference)
//
#include <hip/hip_runtime.h>

// Fused: linear(12->1)+tanh -> LSTM(1->7) -> LSTM(7->7) -> linear(14->1)
// One thread per batch element; weights via uniform (scalar-cache) loads;
// all state in registers; single pass over HBM.

static __device__ __forceinline__ float fexp2(float x) { return __builtin_amdgcn_exp2f(x); }
static __device__ __forceinline__ float frcp(float x)  { return __builtin_amdgcn_rcpf(x); }
// sigmoid(x) = 1/(1+exp(-x)) = rcp(1 + exp2(-x*log2e))
static __device__ __forceinline__ float sigm(float x)  {
    return frcp(1.0f + fexp2(-1.4426950408889634f * x));
}
// tanh(x) = 1 - 2/(exp2(2x*log2e)+1); exact limits at +/-inf
static __device__ __forceinline__ float tanhh(float x) {
    return 1.0f - 2.0f * frcp(fexp2(2.8853900817779268f * x) + 1.0f);
}

#define TT 14
#define FF 12
#define HH 7

__global__ __launch_bounds__(256)
void lstm_fused_kernel(const float* __restrict__ x,
                       const float* __restrict__ w1,   const float* __restrict__ b1,
                       const float* __restrict__ wih0, const float* __restrict__ whh0,
                       const float* __restrict__ bih0, const float* __restrict__ bhh0,
                       const float* __restrict__ wih1, const float* __restrict__ whh1,
                       const float* __restrict__ bih1, const float* __restrict__ bhh1,
                       const float* __restrict__ w2,   const float* __restrict__ b2,
                       float* __restrict__ out, int Bn)
{
    const int b = blockIdx.x * blockDim.x + threadIdx.x;
    if (b >= Bn) return;
    const float* xb = x + (size_t)b * (TT * FF);

    float h0[HH], c0[HH], h1[HH], c1[HH];
#pragma unroll
    for (int j = 0; j < HH; ++j) { h0[j] = 0.f; c0[j] = 0.f; h1[j] = 0.f; c1[j] = 0.f; }

#pragma unroll 1
    for (int t = 0; t < TT; ++t) {
        // ---- linear_1 + tanh: xt = tanh(dot(x[b,t,:], w1) + b1) ----
        const float4* xv = reinterpret_cast<const float4*>(xb + t * FF);
        float4 a0 = xv[0], a1 = xv[1], a2 = xv[2];
        float acc = b1[0];
        acc = fmaf(a0.x, w1[0], acc);  acc = fmaf(a0.y, w1[1], acc);
        acc = fmaf(a0.z, w1[2], acc);  acc = fmaf(a0.w, w1[3], acc);
        acc = fmaf(a1.x, w1[4], acc);  acc = fmaf(a1.y, w1[5], acc);
        acc = fmaf(a1.z, w1[6], acc);  acc = fmaf(a1.w, w1[7], acc);
        acc = fmaf(a2.x, w1[8], acc);  acc = fmaf(a2.y, w1[9], acc);
        acc = fmaf(a2.z, w1[10], acc); acc = fmaf(a2.w, w1[11], acc);
        const float xt = tanhh(acc);

        // ---- LSTM layer 0 (input dim 1), gate order i,f,g,o ----
        float nh0[HH], nc0[HH];
#pragma unroll
        for (int j = 0; j < HH; ++j) {
            float zi = bih0[j]        + bhh0[j]        + xt * wih0[j];
            float zf = bih0[j + HH]   + bhh0[j + HH]   + xt * wih0[j + HH];
            float zg = bih0[j + 2*HH] + bhh0[j + 2*HH] + xt * wih0[j + 2*HH];
            float zo = bih0[j + 3*HH] + bhh0[j + 3*HH] + xt * wih0[j + 3*HH];
#pragma unroll
            for (int k = 0; k < HH; ++k) {
                zi = fmaf(h0[k], whh0[(j       ) * HH + k], zi);
                zf = fmaf(h0[k], whh0[(j + HH  ) * HH + k], zf);
                zg = fmaf(h0[k], whh0[(j + 2*HH) * HH + k], zg);
                zo = fmaf(h0[k], whh0[(j + 3*HH) * HH + k], zo);
            }
            const float ii = sigm(zi), ff = sigm(zf), gg = tanhh(zg), oo = sigm(zo);
            nc0[j] = ff * c0[j] + ii * gg;
            nh0[j] = oo * tanhh(nc0[j]);
        }

        // ---- LSTM layer 1 (input = nh0) ----
        float nh1[HH], nc1[HH];
#pragma unroll
        for (int j = 0; j < HH; ++j) {
            float zi = bih1[j]        + bhh1[j];
            float zf = bih1[j + HH]   + bhh1[j + HH];
            float zg = bih1[j + 2*HH] + bhh1[j + 2*HH];
            float zo = bih1[j + 3*HH] + bhh1[j + 3*HH];
#pragma unroll
            for (int k = 0; k < HH; ++k) {
                zi = fmaf(nh0[k], wih1[(j       ) * HH + k], zi);
                zf = fmaf(nh0[k], wih1[(j + HH  ) * HH + k], zf);
                zg = fmaf(nh0[k], wih1[(j + 2*HH) * HH + k], zg);
                zo = fmaf(nh0[k], wih1[(j + 3*HH) * HH + k], zo);
                zi = fmaf(h1[k],  whh1[(j       ) * HH + k], zi);
                zf = fmaf(h1[k],  whh1[(j + HH  ) * HH + k], zf);
                zg = fmaf(h1[k],  whh1[(j + 2*HH) * HH + k], zg);
                zo = fmaf(h1[k],  whh1[(j + 3*HH) * HH + k], zo);
            }
            const float ii = sigm(zi), ff = sigm(zf), gg = tanhh(zg), oo = sigm(zo);
            nc1[j] = ff * c1[j] + ii * gg;
            nh1[j] = oo * tanhh(nc1[j]);
        }

#pragma unroll
        for (int j = 0; j < HH; ++j) {
            h0[j] = nh0[j]; c0[j] = nc0[j];
            h1[j] = nh1[j]; c1[j] = nc1[j];
        }
    }

    // ---- linear_2 on concat(h_layer0_final, h_layer1_final) ----
    float r = b2[0];
#pragma unroll
    for (int j = 0; j < HH; ++j) r = fmaf(h0[j], w2[j], r);
#pragma unroll
    for (int j = 0; j < HH; ++j) r = fmaf(h1[j], w2[HH + j], r);
    out[b] = r;
}

extern "C" void kernel_launch(void* const* d_in, const int* in_sizes, int n_in,
                              void* d_out, int out_size, void* d_ws, size_t ws_size,
                              hipStream_t stream)
{
    const float* x    = (const float*)d_in[0];
    const float* w1   = (const float*)d_in[1];
    const float* b1   = (const float*)d_in[2];
    const float* wih0 = (const float*)d_in[3];
    const float* whh0 = (const float*)d_in[4];
    const float* bih0 = (const float*)d_in[5];
    const float* bhh0 = (const float*)d_in[6];
    const float* wih1 = (const float*)d_in[7];
    const float* whh1 = (const float*)d_in[8];
    const float* bih1 = (const float*)d_in[9];
    const float* bhh1 = (const float*)d_in[10];
    const float* w2   = (const float*)d_in[11];
    const float* b2   = (const float*)d_in[12];
    float* out = (float*)d_out;

    const int Bn = in_sizes[0] / (TT * FF);
    dim3 grid((Bn + 255) / 256), block(256);
    hipLaunchKernelGGL(lstm_fused_kernel, grid, block, 0, stream,
                       x, w1, b1, wih0, whh0, bih0, bhh0,
                       wih1, whh1, bih1, bhh1, w2, b2, out, Bn);
}